// Round 1
// baseline (5433.759 us; speedup 1.0000x reference)
//
#include <hip/hip_runtime.h>
#include <hip/hip_bf16.h>

// Problem constants
#define T_LEN 2048
#define BATCH 64
#define DIM   256  // D
#define HID   256  // H

using f16   = _Float16;
using f16x4 = __attribute__((ext_vector_type(4))) _Float16;
using f16x8 = __attribute__((ext_vector_type(8))) _Float16;
using f32x4 = __attribute__((ext_vector_type(4))) float;

// ---------------------------------------------------------------------------
// Kernel 1: xproj GEMM.  out[m*512 + n] = sum_k x[m,k] * W[n,k] + bias[n]
//   m = b*T + t  (131072 rows), n in [0,512): n<256 -> forward W_ih_f, else W_ih_r.
//   Written directly into d_out's "outputs" region; the scan kernel overwrites
//   it in place with tanh activations.
// Tile: BM=64, BN=64, BK=64, 256 threads (4 waves, 2x2 of 32x32 per wave),
// f16 MFMA 16x16x32, XOR-swizzled LDS (16B chunk ^ row&7).
// ---------------------------------------------------------------------------
__global__ __launch_bounds__(256) void xproj_gemm(
    const float* __restrict__ x, const float* __restrict__ Wf,
    const float* __restrict__ Wr, const float* __restrict__ bf,
    const float* __restrict__ br, float* __restrict__ out)
{
    __shared__ __align__(16) f16 As[64 * 64];
    __shared__ __align__(16) f16 Bs[64 * 64];

    const int tid = threadIdx.x;
    const int bx = blockIdx.x;          // 2048 M-tiles
    const int by = blockIdx.y;          // 8 N-tiles
    const long m0 = (long)bx * 64;
    const int  n0 = by * 64;
    const float* Bsrc = (by < 4) ? (Wf + (long)n0 * DIM)
                                 : (Wr + (long)(n0 - 256) * DIM);

    const int w  = tid >> 6;            // wave 0..3
    const int l  = tid & 63;
    const int wm = (w & 1) * 32;
    const int wn = (w >> 1) * 32;

    f32x4 acc[2][2] = {};

    for (int kk = 0; kk < DIM; kk += 64) {
        __syncthreads();
        // Stage A (x) and B (weights) tiles, fp32 -> f16, swizzled.
        #pragma unroll
        for (int p = 0; p < 4; ++p) {
            int q    = tid + 256 * p;   // float4 slot 0..1023
            int row  = q >> 4;          // 0..63
            int k4   = q & 15;          // float4 index within 64-float row
            int c    = k4 >> 1;         // 16B chunk (8 f16)
            int half = k4 & 1;
            int cs   = c ^ (row & 7);

            float4 va = *(const float4*)(x + (m0 + row) * DIM + kk + k4 * 4);
            f16x4 ha = { (f16)va.x, (f16)va.y, (f16)va.z, (f16)va.w };
            *(f16x4*)(&As[row * 64 + cs * 8 + half * 4]) = ha;

            float4 vb = *(const float4*)(Bsrc + row * DIM + kk + k4 * 4);
            f16x4 hb = { (f16)vb.x, (f16)vb.y, (f16)vb.z, (f16)vb.w };
            *(f16x4*)(&Bs[row * 64 + cs * 8 + half * 4]) = hb;
        }
        __syncthreads();

        #pragma unroll
        for (int kt = 0; kt < 2; ++kt) {    // two K=32 MFMA steps per LDS tile
            f16x8 a[2], b[2];
            #pragma unroll
            for (int im = 0; im < 2; ++im) {
                int row = wm + im * 16 + (l & 15);
                int c   = (kt * 4 + (l >> 4)) ^ (row & 7);
                a[im] = *(const f16x8*)(&As[row * 64 + c * 8]);
            }
            #pragma unroll
            for (int in = 0; in < 2; ++in) {
                int row = wn + in * 16 + (l & 15);
                int c   = (kt * 4 + (l >> 4)) ^ (row & 7);
                b[in] = *(const f16x8*)(&Bs[row * 64 + c * 8]);
            }
            #pragma unroll
            for (int im = 0; im < 2; ++im)
                #pragma unroll
                for (int in = 0; in < 2; ++in)
                    acc[im][in] = __builtin_amdgcn_mfma_f32_16x16x32_f16(
                        a[im], b[in], acc[im][in], 0, 0, 0);
        }
    }

    // Epilogue: +bias, store fp32. C/D layout: col = l&15, row = (l>>4)*4 + r.
    #pragma unroll
    for (int im = 0; im < 2; ++im) {
        #pragma unroll
        for (int in = 0; in < 2; ++in) {
            int n = n0 + wn + in * 16 + (l & 15);
            float bias = (n < 256) ? bf[n] : br[n - 256];
            #pragma unroll
            for (int r = 0; r < 4; ++r) {
                long m = m0 + wm + im * 16 + ((l >> 4) * 4 + r);
                out[m * 512 + n] = acc[im][in][r] + bias;
            }
        }
    }
}

// ---------------------------------------------------------------------------
// Kernel 2: sequential scan. 128 blocks = one per (batch, direction) chain.
// Thread i owns output element i and W_hh row i in 64 float4 registers.
// h broadcast via LDS double buffer; one barrier per step.
// Reads xp from d_out (written by kernel 1) and overwrites in place with h.
// ---------------------------------------------------------------------------
__device__ __forceinline__ float tanh_fast(float x)
{
    float xc = fminf(fmaxf(x, -15.0f), 15.0f);
    float e  = __expf(2.0f * xc);
    return (e - 1.0f) / (e + 1.0f);
}

__global__ __launch_bounds__(256, 1) void rnn_scan(
    float* __restrict__ out,            // outputs region of d_out (holds xp)
    const float* __restrict__ hidden,   // [2, B, H]
    const float* __restrict__ Whf, const float* __restrict__ Whr,
    float* __restrict__ hid_out)        // d_out + B*T*512
{
    __shared__ __align__(16) float hbuf[2][HID];

    const int i   = threadIdx.x;        // output element 0..255
    const int b   = blockIdx.x & 63;
    const int dir = blockIdx.x >> 6;

    // Weight row i into registers (256 VGPRs).
    const float* W = (dir ? Whr : Whf) + (long)i * HID;
    float4 w[64];
    #pragma unroll
    for (int jj = 0; jj < 64; ++jj)
        w[jj] = *(const float4*)(W + jj * 4);

    hbuf[0][i] = hidden[((long)dir * BATCH + b) * HID + i];
    __syncthreads();

    // element address for (t): base[t*512];  t = dir ? T-1-s : s
    float* base = out + (long)b * T_LEN * 512 + dir * 256 + i;

    // Prefetch ring, depth 4.
    float xr[4];
    #pragma unroll
    for (int u = 0; u < 4; ++u) {
        int t = dir ? (T_LEN - 1 - u) : u;
        xr[u] = base[(long)t * 512];
    }

    float hn = 0.0f;
    for (int s0 = 0; s0 < T_LEN; s0 += 4) {
        #pragma unroll
        for (int u = 0; u < 4; ++u) {
            const int s = s0 + u;
            float cur = xr[u];
            // Prefetch xp[s+4] (clamped; clamp target not yet overwritten).
            int sp = (s + 4 < T_LEN) ? (s + 4) : (T_LEN - 1);
            int tp = dir ? (T_LEN - 1 - sp) : sp;
            xr[u] = base[(long)tp * 512];

            // 256-wide dot: h (LDS broadcast) . w (registers), 4 acc chains.
            const float* hb = hbuf[s & 1];
            float a0 = cur, a1 = 0.0f, a2 = 0.0f, a3 = 0.0f;
            #pragma unroll
            for (int jj = 0; jj < 64; ++jj) {
                float4 h4 = *(const float4*)(hb + jj * 4);
                a0 = fmaf(h4.x, w[jj].x, a0);
                a1 = fmaf(h4.y, w[jj].y, a1);
                a2 = fmaf(h4.z, w[jj].z, a2);
                a3 = fmaf(h4.w, w[jj].w, a3);
            }
            hn = tanh_fast((a0 + a1) + (a2 + a3));

            hbuf[(s + 1) & 1][i] = hn;
            int t = dir ? (T_LEN - 1 - s) : s;
            base[(long)t * 512] = hn;   // overwrite xp with activation
            __syncthreads();
        }
    }

    hid_out[((long)dir * BATCH + b) * HID + i] = hn;
}

// ---------------------------------------------------------------------------
extern "C" void kernel_launch(void* const* d_in, const int* in_sizes, int n_in,
                              void* d_out, int out_size, void* d_ws, size_t ws_size,
                              hipStream_t stream)
{
    const float* x      = (const float*)d_in[0];  // [B,T,D]
    const float* hidden = (const float*)d_in[1];  // [2,B,H]
    const float* W_ih_f = (const float*)d_in[2];  // [H,D]
    const float* W_hh_f = (const float*)d_in[3];  // [H,H]
    const float* b_f    = (const float*)d_in[4];  // [H]
    const float* W_ih_r = (const float*)d_in[5];
    const float* W_hh_r = (const float*)d_in[6];
    const float* b_r    = (const float*)d_in[7];

    float* outp    = (float*)d_out;                       // [B,T,512]
    float* hid_out = outp + (long)BATCH * T_LEN * 512;    // [2,B,H]

    // Phase 1: xp = x @ [W_ih_f; W_ih_r]^T + bias, into d_out (fp32).
    xproj_gemm<<<dim3((BATCH * T_LEN) / 64, 512 / 64), 256, 0, stream>>>(
        x, W_ih_f, W_ih_r, b_f, b_r, outp);

    // Phase 2: 128 independent recurrent chains, in-place tanh scan.
    rnn_scan<<<dim3(2 * BATCH), 256, 0, stream>>>(
        outp, hidden, W_hh_f, W_hh_r, hid_out);
}

// Round 3
// 2497.749 us; speedup vs baseline: 2.1755x; 2.1755x over previous
//
#include <hip/hip_runtime.h>
#include <hip/hip_bf16.h>

#define T_LEN 2048
#define BATCH 64
#define DIM   256  // D
#define HID   256  // H

using f16    = _Float16;
using f16x8  = __attribute__((ext_vector_type(8))) _Float16;
using fp16x2 = __attribute__((ext_vector_type(2))) __fp16;   // cvt_pkrtz result type
using f32x4  = __attribute__((ext_vector_type(4))) float;

__device__ __forceinline__ f16x8 pack8(float4 a, float4 b)
{
    fp16x2 p0 = __builtin_amdgcn_cvt_pkrtz(a.x, a.y);
    fp16x2 p1 = __builtin_amdgcn_cvt_pkrtz(a.z, a.w);
    fp16x2 p2 = __builtin_amdgcn_cvt_pkrtz(b.x, b.y);
    fp16x2 p3 = __builtin_amdgcn_cvt_pkrtz(b.z, b.w);
    f16x8 r = { (f16)p0.x, (f16)p0.y, (f16)p1.x, (f16)p1.y,
                (f16)p2.x, (f16)p2.y, (f16)p3.x, (f16)p3.y };
    return r;
}

// ---------------------------------------------------------------------------
// Kernel 1: xp = x @ [W_ih_f; W_ih_r]^T + bias  -> d_out (fp32, in-place for scan)
// BM=128, BN=128, BK=64, 256 threads (4 waves, each 64x64 = 4x4 of 16x16).
// f32->f16 packed staging, XOR-swizzled LDS.
// ---------------------------------------------------------------------------
__global__ __launch_bounds__(256) void xproj_gemm(
    const float* __restrict__ x, const float* __restrict__ Wf,
    const float* __restrict__ Wr, const float* __restrict__ bf,
    const float* __restrict__ br, float* __restrict__ out)
{
    __shared__ __align__(16) f16 As[128 * 64];
    __shared__ __align__(16) f16 Bs[128 * 64];

    const int tid = threadIdx.x;
    const long m0 = (long)blockIdx.x * 128;
    const int  n0 = blockIdx.y * 128;          // {0,128,256,384}
    const float* Bsrc = (n0 < 256) ? (Wf + (long)n0 * DIM)
                                   : (Wr + (long)(n0 - 256) * DIM);
    const int w = tid >> 6, l = tid & 63;
    const int wm = (w & 1) * 64, wn = (w >> 1) * 64;
    const int srow = tid >> 1, sseg = tid & 1;   // staging: 2 threads/row

    f32x4 acc[4][4] = {};

    for (int kk = 0; kk < DIM; kk += 64) {
        __syncthreads();
        {   // stage A (x rows)
            const float* sa = x + (m0 + srow) * DIM + kk + sseg * 32;
            #pragma unroll
            for (int q = 0; q < 4; ++q) {
                float4 u0 = ((const float4*)sa)[q * 2];
                float4 u1 = ((const float4*)sa)[q * 2 + 1];
                int c = (sseg * 4 + q) ^ (srow & 7);
                *(f16x8*)(&As[srow * 64 + c * 8]) = pack8(u0, u1);
            }
        }
        {   // stage B (weight rows)
            const float* sb = Bsrc + (long)srow * DIM + kk + sseg * 32;
            #pragma unroll
            for (int q = 0; q < 4; ++q) {
                float4 u0 = ((const float4*)sb)[q * 2];
                float4 u1 = ((const float4*)sb)[q * 2 + 1];
                int c = (sseg * 4 + q) ^ (srow & 7);
                *(f16x8*)(&Bs[srow * 64 + c * 8]) = pack8(u0, u1);
            }
        }
        __syncthreads();

        #pragma unroll
        for (int kt = 0; kt < 2; ++kt) {
            f16x8 a[4], b[4];
            #pragma unroll
            for (int im = 0; im < 4; ++im) {
                int row = wm + im * 16 + (l & 15);
                int c   = (kt * 4 + (l >> 4)) ^ (row & 7);
                a[im] = *(const f16x8*)(&As[row * 64 + c * 8]);
            }
            #pragma unroll
            for (int in = 0; in < 4; ++in) {
                int row = wn + in * 16 + (l & 15);
                int c   = (kt * 4 + (l >> 4)) ^ (row & 7);
                b[in] = *(const f16x8*)(&Bs[row * 64 + c * 8]);
            }
            #pragma unroll
            for (int im = 0; im < 4; ++im)
                #pragma unroll
                for (int in = 0; in < 4; ++in)
                    acc[im][in] = __builtin_amdgcn_mfma_f32_16x16x32_f16(
                        a[im], b[in], acc[im][in], 0, 0, 0);
        }
    }

    #pragma unroll
    for (int im = 0; im < 4; ++im)
        #pragma unroll
        for (int in = 0; in < 4; ++in) {
            int n = n0 + wn + in * 16 + (l & 15);
            float bias = (n < 256) ? bf[n] : br[n - 256];
            #pragma unroll
            for (int r = 0; r < 4; ++r) {
                long m = m0 + wm + im * 16 + ((l >> 4) * 4 + r);
                out[m * 512 + n] = acc[im][in][r] + bias;
            }
        }
}

// ---------------------------------------------------------------------------
// Kernel 2: MFMA scan. 8 blocks x 256 threads; block = 16 chains of one dir.
// Per step: h_new[16,256] = tanh(xp + h[16,256] @ W_hh^T) via 16x16x32 f16 MFMA.
// W_hh B-frags resident in 128 VGPRs/wave; h double-buffered in LDS (swizzled);
// xp read from d_out and overwritten in place with outputs.
// Raw s_barrier + lgkmcnt(0) only: global stores/prefetches never drained.
// ---------------------------------------------------------------------------
__global__ __launch_bounds__(256, 1) void rnn_scan(
    float* __restrict__ out, const float* __restrict__ hidden,
    const float* __restrict__ Whf, const float* __restrict__ Whr,
    float* __restrict__ hid_out)
{
    __shared__ __align__(16) f16 hbuf[2][16 * 256];

    const int tid = threadIdx.x;
    const int g   = blockIdx.x;        // 0..7
    const int dir = g >> 2;
    const int b0  = (g & 3) * 16;
    const int w   = tid >> 6, l = tid & 63;
    const int c15 = l & 15, hi = l >> 4;

    // W_hh B-fragments: lane l -> col n = 64w+16nt+c15, k = 32kt+8hi+j.
    const float* Wh = dir ? Whr : Whf;
    f16x8 Bhh[4][8];
    #pragma unroll
    for (int nt = 0; nt < 4; ++nt) {
        int n = w * 64 + nt * 16 + c15;
        #pragma unroll
        for (int kt = 0; kt < 8; ++kt) {
            const float* p = Wh + (long)n * HID + kt * 32 + hi * 8;
            float4 u0 = ((const float4*)p)[0];
            float4 u1 = ((const float4*)p)[1];
            f16x8 r = { (f16)u0.x, (f16)u0.y, (f16)u0.z, (f16)u0.w,
                        (f16)u1.x, (f16)u1.y, (f16)u1.z, (f16)u1.w };
            Bhh[nt][kt] = r;
        }
    }

    // initial h -> hbuf[0] (f16, swizzled): thread covers chain=tid>>4, 16 cols
    {
        int chain = tid >> 4;
        int cbase = (tid & 15) * 16;
        const float* hp = hidden + ((long)dir * BATCH + b0 + chain) * HID + cbase;
        #pragma unroll
        for (int cc = 0; cc < 2; ++cc) {
            float4 u0 = ((const float4*)hp)[cc * 2];
            float4 u1 = ((const float4*)hp)[cc * 2 + 1];
            f16x8 r = { (f16)u0.x, (f16)u0.y, (f16)u0.z, (f16)u0.w,
                        (f16)u1.x, (f16)u1.y, (f16)u1.z, (f16)u1.w };
            int c  = (cbase >> 3) + cc;
            int cs = c ^ (chain & 7);
            *(f16x8*)(&hbuf[0][chain * 256 + cs * 8]) = r;
        }
    }

    // xp/output byte offsets: lane holds (chain = 4hi+r, col = 64w+16nt+c15)
    unsigned off[4][4];
    float    xr[4][4];
    const int t0 = dir ? (T_LEN - 1) : 0;
    #pragma unroll
    for (int nt = 0; nt < 4; ++nt)
        #pragma unroll
        for (int r = 0; r < 4; ++r) {
            int chain = hi * 4 + r;
            int col   = w * 64 + nt * 16 + c15;
            off[nt][r] = (unsigned)((((b0 + chain) * T_LEN + t0) * 512
                                     + dir * 256 + col) * 4);
            xr[nt][r] = *(const float*)((const char*)out + off[nt][r]);
        }

    __syncthreads();

    const int sdelta = dir ? -2048 : 2048;   // +/- one timestep (512 f32)
    float hlast[4][4];

    for (int s = 0; s < T_LEN; ++s) {
        const f16* rb = hbuf[s & 1];
        f16*       wb = hbuf[(s + 1) & 1];
        const int d = (s == T_LEN - 1) ? 0 : sdelta;

        // acc <- xp (bias already folded in by the GEMM)
        f32x4 acc[4];
        #pragma unroll
        for (int nt = 0; nt < 4; ++nt)
            #pragma unroll
            for (int r = 0; r < 4; ++r)
                acc[nt][r] = xr[nt][r];

        // prefetch next step's xp (slot untouched until step s+1; value at
        // d==0 is discarded, so the same-address overlap at the tail is benign)
        #pragma unroll
        for (int nt = 0; nt < 4; ++nt)
            #pragma unroll
            for (int r = 0; r < 4; ++r) {
                off[nt][r] += d;
                xr[nt][r] = *(const float*)((const char*)out + off[nt][r]);
            }

        // h A-fragments: row = chain = c15, k-chunk c = 4kt+hi, swizzled
        f16x8 hfrag[8];
        #pragma unroll
        for (int kt = 0; kt < 8; ++kt) {
            int cs = ((kt * 4 + hi) ^ (c15 & 7));
            hfrag[kt] = *(const f16x8*)(&rb[c15 * 256 + cs * 8]);
        }

        #pragma unroll
        for (int kt = 0; kt < 8; ++kt)
            #pragma unroll
            for (int nt = 0; nt < 4; ++nt)
                acc[nt] = __builtin_amdgcn_mfma_f32_16x16x32_f16(
                    hfrag[kt], Bhh[nt][kt], acc[nt], 0, 0, 0);

        // epilogue: tanh, store f32 out (fire-and-forget), f16 h -> LDS
        #pragma unroll
        for (int nt = 0; nt < 4; ++nt)
            #pragma unroll
            for (int r = 0; r < 4; ++r) {
                float p  = acc[nt][r];
                float e  = __builtin_amdgcn_exp2f(p * 2.885390081777927f);
                float hn = fmaf(-2.0f, __builtin_amdgcn_rcpf(e + 1.0f), 1.0f);
                hlast[nt][r] = hn;
                *(float*)((char*)out + (off[nt][r] - d)) = hn;

                int chain = hi * 4 + r;
                int col   = w * 64 + nt * 16 + c15;
                int cs    = (col >> 3) ^ (chain & 7);
                wb[chain * 256 + cs * 8 + (col & 7)] = (f16)hn;
            }

        asm volatile("s_waitcnt lgkmcnt(0)" ::: "memory");
        __builtin_amdgcn_sched_barrier(0);
        __builtin_amdgcn_s_barrier();
        __builtin_amdgcn_sched_barrier(0);
    }

    #pragma unroll
    for (int nt = 0; nt < 4; ++nt)
        #pragma unroll
        for (int r = 0; r < 4; ++r) {
            int chain = hi * 4 + r;
            int col   = w * 64 + nt * 16 + c15;
            hid_out[((long)dir * BATCH + b0 + chain) * HID + col] = hlast[nt][r];
        }
}

// ---------------------------------------------------------------------------
extern "C" void kernel_launch(void* const* d_in, const int* in_sizes, int n_in,
                              void* d_out, int out_size, void* d_ws, size_t ws_size,
                              hipStream_t stream)
{
    const float* x      = (const float*)d_in[0];  // [B,T,D]
    const float* hidden = (const float*)d_in[1];  // [2,B,H]
    const float* W_ih_f = (const float*)d_in[2];  // [H,D]
    const float* W_hh_f = (const float*)d_in[3];  // [H,H]
    const float* b_f    = (const float*)d_in[4];  // [H]
    const float* W_ih_r = (const float*)d_in[5];
    const float* W_hh_r = (const float*)d_in[6];
    const float* b_r    = (const float*)d_in[7];

    float* outp    = (float*)d_out;                       // [B,T,512]
    float* hid_out = outp + (long)BATCH * T_LEN * 512;    // [2,B,H]

    xproj_gemm<<<dim3((BATCH * T_LEN) / 128, 512 / 128), 256, 0, stream>>>(
        x, W_ih_f, W_ih_r, b_f, b_r, outp);

    rnn_scan<<<dim3(8), 256, 0, stream>>>(
        outp, hidden, W_hh_f, W_hh_r, hid_out);
}